// Round 1
// baseline (422.963 us; speedup 1.0000x reference)
//
#include <hip/hip_runtime.h>
#include <hip/hip_bf16.h>

typedef __hip_bfloat16 bf16_t;
typedef __attribute__((ext_vector_type(8))) short short8;
typedef __attribute__((ext_vector_type(16))) float floatx16;

static __device__ __forceinline__ float b2f(bf16_t v) { return __bfloat162float(v); }
static __device__ __forceinline__ bf16_t f2b(float v) { return __float2bfloat16(v); }
static __device__ __forceinline__ float us2f(unsigned short u) {
    union { unsigned int i; float f; } c; c.i = ((unsigned int)u) << 16; return c.f;
}

// Problem constants
#define NN 50000
#define EE 200000
#define GG 2048
#define BCAP 64   // in-degree cap; mean deg = 4

union U4 { uint4 v; unsigned short s[8]; };

#define FZ16 {0.f,0.f,0.f,0.f,0.f,0.f,0.f,0.f,0.f,0.f,0.f,0.f,0.f,0.f,0.f,0.f}

// 32x32x16 fragment-major layout (A and B operands share it):
//   element (i, k) of an [I x K] K-major matrix lives at
//   ((i/32 * (K/16) + k/16) * 64 + ((k%16)/8)*32 + i%32) * 8 + k%8
// One wave fragment = 64 lanes x short8 = contiguous 1KB.

// ---------------------------------------------------------------------------
// Inverted adjacency build
// ---------------------------------------------------------------------------
__global__ void build_buckets(const int* __restrict__ ei, int* __restrict__ cnt,
                              int* __restrict__ bkt, int E) {
    int e = blockIdx.x * 256 + threadIdx.x;
    if (e >= E) return;
    int s = ei[e];
    int d = ei[E + e];
    int pos = atomicAdd(&cnt[d], 1);
    if (pos < BCAP) bkt[d * BCAP + pos] = s;
}

// ---------------------------------------------------------------------------
// h2[n] = relu(init[n] + sum nbr y2)   (bf16 [N,128] row-major in/out)
// ---------------------------------------------------------------------------
__global__ void gather_relu_b16(const bf16_t* __restrict__ y2, const bf16_t* __restrict__ init,
                                const int* __restrict__ cnt, const int* __restrict__ bkt,
                                bf16_t* __restrict__ h2) {
    int t = blockIdx.x * 256 + threadIdx.x;
    int n = t >> 4;
    if (n >= NN) return;
    int j = (t & 15) * 8;
    int c = cnt[n]; if (c > BCAP) c = BCAP;
    const int* bp = bkt + n * BCAP;
    U4 u; u.v = *(const uint4*)(init + n * 128 + j);
    float s[8];
    #pragma unroll
    for (int k = 0; k < 8; ++k) s[k] = us2f(u.s[k]);
    for (int i = 0; i < c; ++i) {
        U4 w; w.v = *(const uint4*)(y2 + (size_t)bp[i] * 128 + j);
        #pragma unroll
        for (int k = 0; k < 8; ++k) s[k] += us2f(w.s[k]);
    }
    alignas(16) bf16_t ob[8];
    #pragma unroll
    for (int k = 0; k < 8; ++k) ob[k] = f2b(fmaxf(s[k], 0.f));
    *(uint4*)(h2 + n * 128 + j) = *(const uint4*)ob;
}

// outF[n] += sum nbr y4   (f32 [N,64] row-major, in-place on d_out)
__global__ void gather_add_f32_64(const float* __restrict__ y4, const int* __restrict__ cnt,
                                  const int* __restrict__ bkt, float* __restrict__ outF) {
    int t = blockIdx.x * 256 + threadIdx.x;
    int n = t >> 4;
    if (n >= NN) return;
    int j = (t & 15) * 4;
    int c = cnt[n]; if (c > BCAP) c = BCAP;
    const int* bp = bkt + n * BCAP;
    float4 sum = *(const float4*)(outF + n * 64 + j);
    for (int i = 0; i < c; ++i) {
        float4 v = *(const float4*)(y4 + (size_t)bp[i] * 64 + j);
        sum.x += v.x; sum.y += v.y; sum.z += v.z; sum.w += v.w;
    }
    *(float4*)(outF + n * 64 + j) = sum;
}

// ---------------------------------------------------------------------------
// Fused gather + two-GEMM v7: 32x32x16 MFMA (2x MACs per LDS byte vs v6),
// 256-hcol chunks (4 instead of 8 -> A-tile re-read halved).
//   Block = 64 nodes (2 node-tiles of 32), 512 threads = 8 waves.
//   Stage 1: wave wn owns hcol-tile (ci*8+wn) x BOTH node tiles
//            -> each W1 frag read exactly once per block.
//   H chunk [64 x 256] bf16, single-buffered (32KB), frag-major.
//   Stage 2: wave (og=wn>>1, wr=wn&1): OCT2 out-tiles x node-tile wr.
// LDS reads/block: 1.5MB (v6: 3MB).  LDS total 70144B (K=256) -> 2 blk/CU.
// Outputs: outcol < NOUT/2 -> yout, else -> initout (+bias2).
// ---------------------------------------------------------------------------
template <int K, int NOUT, int F32OUT, int SRCF32>
__global__ __launch_bounds__(512, 4) void fused7(
    const void* __restrict__ src, const int* __restrict__ cnt,
    const int* __restrict__ bkt,
    const bf16_t* __restrict__ W1f, const float* __restrict__ bias1,
    const bf16_t* __restrict__ W2f, const float* __restrict__ bias2,
    void* __restrict__ yout, void* __restrict__ initout)
{
    constexpr int KT16 = K / 16;      // A k-tiles (16-deep)
    constexpr int OT32 = NOUT / 32;   // out 32-col tiles (4 or 8)
    constexpr int OCT2 = OT32 / 4;    // out tiles per wave (1 or 2)
    constexpr int OH   = NOUT / 2;
    constexpr int SW   = K / 2;       // source row width (64 f32 / 128 bf16)
    constexpr int HALF = K / 16;      // 8-col groups per half (8 or 16)
    __shared__ float b1sl[1024];
    __shared__ float b2sl[128];
    __shared__ __align__(16) bf16_t Asl[64 * K];     // frag-major A tile
    __shared__ __align__(16) bf16_t Hsl[64 * 256];   // frag-major H chunk (single buf)

    const int tid  = threadIdx.x;
    const int lane = tid & 63;
    const int wn   = tid >> 6;        // 0..7
    const int l31  = lane & 31;
    const int hi   = lane >> 5;
    const int og   = wn >> 1;         // stage-2 out-col group 0..3
    const int wr   = wn & 1;          // stage-2 node-tile 0..1
    const int bm0  = blockIdx.x * 64;

    for (int i = tid; i < 1024; i += 512) b1sl[i] = (i < 1000) ? bias1[i] : 0.f;
    if (tid < OH) b2sl[tid] = bias2[tid];

    // ---- prologue: gather + own-copy directly into Asl (frag-major)
    // tasks [0, 64*HALF): gather-sum slot; [64*HALF, 2*64*HALF): own-copy.
    #pragma unroll
    for (int it = 0; it < (2 * 64 * HALF) / 512; ++it) {
        int task = it * 512 + tid;
        const bool own = task >= 64 * HALF;
        int t2 = own ? task - 64 * HALF : task;
        int i = t2 / HALF, s = t2 - (t2 / HALF) * HALF;
        int n = bm0 + i;
        int j = s * 8;
        float sum[8] = {0.f, 0.f, 0.f, 0.f, 0.f, 0.f, 0.f, 0.f};
        if (n < NN) {
            if (!own) {
                int c = cnt[n]; if (c > BCAP) c = BCAP;
                const int* bp = bkt + n * BCAP;
                for (int e = 0; e < c; ++e) {
                    int sn = bp[e];
                    if (SRCF32) {
                        const float* r = (const float*)src + (size_t)sn * SW + j;
                        float4 a = *(const float4*)r;
                        float4 b = *(const float4*)(r + 4);
                        sum[0] += a.x; sum[1] += a.y; sum[2] += a.z; sum[3] += a.w;
                        sum[4] += b.x; sum[5] += b.y; sum[6] += b.z; sum[7] += b.w;
                    } else {
                        U4 w; w.v = *(const uint4*)((const bf16_t*)src + (size_t)sn * SW + j);
                        #pragma unroll
                        for (int k = 0; k < 8; ++k) sum[k] += us2f(w.s[k]);
                    }
                }
            } else {
                if (SRCF32) {
                    const float* r = (const float*)src + (size_t)n * SW + j;
                    float4 a = *(const float4*)r;
                    float4 b = *(const float4*)(r + 4);
                    sum[0] = a.x; sum[1] = a.y; sum[2] = a.z; sum[3] = a.w;
                    sum[4] = b.x; sum[5] = b.y; sum[6] = b.z; sum[7] = b.w;
                } else {
                    U4 w; w.v = *(const uint4*)((const bf16_t*)src + (size_t)n * SW + j);
                    #pragma unroll
                    for (int k = 0; k < 8; ++k) sum[k] = us2f(w.s[k]);
                }
            }
        }
        int cc = (own ? K / 2 : 0) + j;           // column in A's K-space
        int off = (((i >> 5) * KT16 + (cc >> 4)) * 64 + ((cc >> 3) & 1) * 32 + (i & 31)) * 8;
        alignas(16) bf16_t ob[8];
        #pragma unroll
        for (int k = 0; k < 8; ++k) ob[k] = f2b(sum[k]);
        *(uint4*)(&Asl[off]) = *(const uint4*)ob;
    }

    floatx16 acc2[OCT2];
    #pragma unroll
    for (int oo = 0; oo < OCT2; ++oo) acc2[oo] = (floatx16)FZ16;

    __syncthreads();   // Asl + biases ready

    for (int ci = 0; ci < 4; ++ci) {
        // ---- stage 1: wave computes h-tile (ci*8 + wn) x both node-tiles
        floatx16 acc1[2];
        acc1[0] = (floatx16)FZ16;
        acc1[1] = (floatx16)FZ16;

        #pragma unroll
        for (int kh = 0; kh < KT16 / 8; ++kh) {
            short8 w1v[8];
            #pragma unroll
            for (int jj = 0; jj < 8; ++jj)
                w1v[jj] = *(const short8*)(W1f + (((size_t)(ci * 8 + wn) * KT16 + kh * 8 + jj) * 64 + lane) * 8);
            #pragma unroll
            for (int jj = 0; jj < 8; ++jj) {
                #pragma unroll
                for (int nt2 = 0; nt2 < 2; ++nt2) {
                    short8 av = *(const short8*)&Asl[((nt2 * KT16 + kh * 8 + jj) * 64 + lane) * 8];
                    acc1[nt2] = __builtin_amdgcn_mfma_f32_32x32x16_bf16(w1v[jj], av, acc1[nt2], 0, 0, 0);
                }
            }
        }

        __syncthreads();   // previous chunk's stage-2 readers done with Hsl

        // bias+relu -> frag-major H; C/D: node=l31, hcol32=(r&3)+8*(r>>2)+4*hi
        #pragma unroll
        for (int nt2 = 0; nt2 < 2; ++nt2) {
            #pragma unroll
            for (int g = 0; g < 4; ++g) {
                float4 bv = *(const float4*)&b1sl[ci * 256 + wn * 32 + 8 * g + 4 * hi];
                const float* bvp = (const float*)&bv;
                alignas(8) bf16_t hb[4];
                #pragma unroll
                for (int e = 0; e < 4; ++e)
                    hb[e] = f2b(fmaxf(acc1[nt2][4 * g + e] + bvp[e], 0.f));
                int off = ((nt2 * 16 + wn * 2 + (g >> 1)) * 64 + (g & 1) * 32 + l31) * 8 + 4 * hi;
                *(uint2*)&Hsl[off] = *(const uint2*)hb;
            }
        }

        __syncthreads();   // H chunk visible

        // ---- stage 2: acc2[oo] += W2(out-tile og*OCT2+oo) x H(node-tile wr)
        #pragma unroll
        for (int ks = 0; ks < 16; ++ks) {
            short8 hf = *(const short8*)&Hsl[((wr * 16 + ks) * 64 + lane) * 8];
            #pragma unroll
            for (int oo = 0; oo < OCT2; ++oo) {
                short8 w2v = *(const short8*)(W2f + (((size_t)(og * OCT2 + oo) * 64 + ci * 16 + ks) * 64 + lane) * 8);
                acc2[oo] = __builtin_amdgcn_mfma_f32_32x32x16_bf16(w2v, hf, acc2[oo], 0, 0, 0);
            }
        }
    }

    // ---- epilogue: D: node=l31 (tile wr), outcol32=(r&3)+8*(r>>2)+4*hi
    int node = bm0 + wr * 32 + l31;
    if (node < NN) {
        #pragma unroll
        for (int oo = 0; oo < OCT2; ++oo) {
            int o = og * OCT2 + oo;
            #pragma unroll
            for (int g = 0; g < 4; ++g) {
                int oc = o * 32 + 8 * g + 4 * hi;   // OH%32==0 -> no tile straddle
                const bool isInit = (oc >= OH);
                int col = isInit ? oc - OH : oc;
                float4 bv = isInit ? *(const float4*)&b2sl[col]
                                   : make_float4(0.f, 0.f, 0.f, 0.f);
                const float* bvp = (const float*)&bv;
                float v[4];
                #pragma unroll
                for (int e = 0; e < 4; ++e) v[e] = acc2[oo][4 * g + e] + bvp[e];
                if (F32OUT) {
                    float* dst = isInit ? (float*)initout : (float*)yout;
                    *(float4*)(dst + (size_t)node * OH + col) = make_float4(v[0], v[1], v[2], v[3]);
                } else {
                    bf16_t* dst = isInit ? (bf16_t*)initout : (bf16_t*)yout;
                    alignas(8) bf16_t ob[4];
                    ob[0] = f2b(v[0]); ob[1] = f2b(v[1]); ob[2] = f2b(v[2]); ob[3] = f2b(v[3]);
                    *(uint2*)(dst + (size_t)node * OH + col) = *(const uint2*)ob;
                }
            }
        }
    }
}

// ---------------------------------------------------------------------------
// Weight packers -> 32x32x16 fragment-major bf16 (tiny, every call)
// ---------------------------------------------------------------------------
__global__ void pack_w1_frag(const float* __restrict__ Wa, const float* __restrict__ Wb,
                             bf16_t* __restrict__ out, int K1, int K2, int total) {
    int idx = blockIdx.x * 256 + threadIdx.x;
    if (idx >= total) return;
    int K = K1 + K2;
    int KT16 = K >> 4;
    int e = idx & 7;
    int l = (idx >> 3) & 63;
    int tile = idx >> 9;
    int kt = tile % KT16, t = tile / KT16;
    int c = t * 32 + (l & 31);
    int k = kt * 16 + (l >> 5) * 8 + e;
    float v = 0.f;
    if (c < 1000) v = (k < K1) ? Wa[c * K1 + k] : Wb[c * K2 + (k - K1)];
    out[idx] = f2b(v);
}
__global__ void pack_w2_frag(const float* __restrict__ Wa, const float* __restrict__ Wb,
                             bf16_t* __restrict__ out, int OH, int total) {
    int idx = blockIdx.x * 256 + threadIdx.x;
    if (idx >= total) return;
    int e = idx & 7;
    int l = (idx >> 3) & 63;
    int tile = idx >> 9;
    int kt2 = tile & 63, o = tile >> 6;   // KT2TOT = 1024/16 = 64
    int c = o * 32 + (l & 31);
    int k = kt2 * 16 + (l >> 5) * 8 + e;
    float v = 0.f;
    if (k < 1000) v = (c < OH) ? Wa[c * 1000 + k] : Wb[(c - OH) * 1000 + k];
    out[idx] = f2b(v);
}

// ---------------------------------------------------------------------------
// Mean-pool per graph (batch sorted; binary search), h2 bf16
// ---------------------------------------------------------------------------
__global__ void pool_kernel(const bf16_t* __restrict__ h2,
                            const int* __restrict__ batch,
                            float* __restrict__ enc, int Nn) {
    int g = blockIdx.x;
    __shared__ int s_lo, s_hi;
    if (threadIdx.x == 0) {
        int lo = 0, hi = Nn;
        while (lo < hi) { int mid = (lo + hi) >> 1; if (batch[mid] < g) lo = mid + 1; else hi = mid; }
        s_lo = lo;
        hi = Nn;
        while (lo < hi) { int mid = (lo + hi) >> 1; if (batch[mid] < g + 1) lo = mid + 1; else hi = mid; }
        s_hi = lo;
    }
    __syncthreads();
    int f = threadIdx.x;
    float sum = 0.f;
    for (int n = s_lo; n < s_hi; ++n) sum += b2f(h2[n * 128 + f]);
    float cnt = (float)((s_hi - s_lo) > 0 ? (s_hi - s_lo) : 1);
    enc[g * 128 + f] = sum / cnt;
}

// ---------------------------------------------------------------------------
// Launch
// ---------------------------------------------------------------------------
extern "C" void kernel_launch(void* const* d_in, const int* in_sizes, int n_in,
                              void* d_out, int out_size, void* d_ws, size_t ws_size,
                              hipStream_t stream) {
    const float* x       = (const float*)d_in[0];
    const int*   ei      = (const int*)d_in[1];
    const int*   batch   = (const int*)d_in[2];
    const float* W1_rel  = (const float*)d_in[3];
    const float* b1      = (const float*)d_in[4];
    const float* W1_root = (const float*)d_in[5];
    const float* W2_rel  = (const float*)d_in[6];
    const float* b2      = (const float*)d_in[7];
    const float* W2_root = (const float*)d_in[8];
    const float* W3_rel  = (const float*)d_in[9];
    const float* b3      = (const float*)d_in[10];
    const float* W3_root = (const float*)d_in[11];
    const float* W4_rel  = (const float*)d_in[12];
    const float* b4      = (const float*)d_in[13];
    const float* W4_root = (const float*)d_in[14];

    float* outF = (float*)d_out;            // [N,64] then [G,128]
    float* enc  = outF + NN * 64;

    char* ws = (char*)d_ws;                         // ~66 MB
    bf16_t* y2buf  = (bf16_t*)(ws + 0);             // [N,128] bf16
    bf16_t* h2init = (bf16_t*)(ws + 12800000ULL);   // [N,128] bf16
    bf16_t* h2buf  = (bf16_t*)(ws + 25600000ULL);   // [N,128] bf16
    float*  y4buf  = (float*)(ws + 38400000ULL);    // [N,64] f32
    int*    cnt    = (int*)(ws + 51200000ULL);      // [N]
    int*    bkt    = (int*)(ws + 51400064ULL);      // [N*64]
    bf16_t* W1f    = (bf16_t*)(ws + 64200064ULL);   // 1024x128 frag-major
    bf16_t* W2f    = (bf16_t*)(ws + 64462208ULL);   // 256x1024 frag-major
    bf16_t* W3f    = (bf16_t*)(ws + 64986496ULL);   // 1024x256 frag-major
    bf16_t* W4f    = (bf16_t*)(ws + 65510784ULL);   // 128x1024 frag-major

    const int RB64 = (NN + 63) / 64;  // 782

    // ---- inverted adjacency (once; reused by all 4 propagations)
    hipMemsetAsync(cnt, 0, NN * sizeof(int), stream);
    build_buckets<<<(EE + 255) / 256, 256, 0, stream>>>(ei, cnt, bkt, EE);

    // ---- pack weights to fragment-major bf16
    pack_w1_frag<<<(1024 * 128) / 256, 256, 0, stream>>>(W1_rel, W1_root, W1f, 64, 64, 1024 * 128);
    pack_w2_frag<<<(256 * 1024) / 256, 256, 0, stream>>>(W2_rel, W2_root, W2f, 128, 256 * 1024);
    pack_w1_frag<<<(1024 * 256) / 256, 256, 0, stream>>>(W3_rel, W3_root, W3f, 128, 128, 1024 * 256);
    pack_w2_frag<<<(128 * 1024) / 256, 256, 0, stream>>>(W4_rel, W4_root, W4f, 64, 128 * 1024);

    // ---- L1+L2 fused (gather in-prologue): A=[gather(x)|x]; h1 on-chip;
    //      y2 = h1@W2_rel^T (bf16), h2init = h1@W2_root^T + b2 (bf16)
    fused7<128, 256, 0, 1><<<RB64, 512, 0, stream>>>(x, cnt, bkt, W1f, b1, W2f, b2, y2buf, h2init);

    // ---- h2 = relu(h2init + gather(y2));  encoded = mean-pool(h2)
    gather_relu_b16<<<(NN * 16 + 255) / 256, 256, 0, stream>>>(y2buf, h2init, cnt, bkt, h2buf);
    pool_kernel<<<GG, 128, 0, stream>>>(h2buf, batch, enc, NN);

    // ---- L3+L4 fused (gather in-prologue): A=[gather(h2)|h2]; h3 on-chip;
    //      y4 = h3@W4_rel^T (f32), outF = h3@W4_root^T + b4 (f32, direct)
    fused7<256, 128, 1, 0><<<RB64, 512, 0, stream>>>(h2buf, cnt, bkt, W3f, b3, W4f, b4, y4buf, outF);

    // ---- out = outF + gather(y4)
    gather_add_f32_64<<<(NN * 16 + 255) / 256, 256, 0, stream>>>(y4buf, cnt, bkt, outF);
}

// Round 2
// 416.089 us; speedup vs baseline: 1.0165x; 1.0165x over previous
//
#include <hip/hip_runtime.h>
#include <hip/hip_bf16.h>

typedef __hip_bfloat16 bf16_t;
typedef __attribute__((ext_vector_type(8))) short short8;
typedef __attribute__((ext_vector_type(16))) float floatx16;

static __device__ __forceinline__ float b2f(bf16_t v) { return __bfloat162float(v); }
static __device__ __forceinline__ bf16_t f2b(float v) { return __float2bfloat16(v); }
static __device__ __forceinline__ float us2f(unsigned short u) {
    union { unsigned int i; float f; } c; c.i = ((unsigned int)u) << 16; return c.f;
}

// Problem constants
#define NN 50000
#define EE 200000
#define GG 2048
#define BCAP 64   // in-degree cap; mean deg = 4

union U4 { uint4 v; unsigned short s[8]; };

#define FZ16 {0.f,0.f,0.f,0.f,0.f,0.f,0.f,0.f,0.f,0.f,0.f,0.f,0.f,0.f,0.f,0.f}

// 32x32x16 fragment-major layout (A and B operands share it):
//   element (i, k) of an [I x K] K-major matrix lives at
//   ((i/32 * (K/16) + k/16) * 64 + ((k%16)/8)*32 + i%32) * 8 + k%8
// One wave fragment = 64 lanes x short8 = contiguous 1KB.

// ---------------------------------------------------------------------------
// Inverted adjacency build
// ---------------------------------------------------------------------------
__global__ void build_buckets(const int* __restrict__ ei, int* __restrict__ cnt,
                              int* __restrict__ bkt, int E) {
    int e = blockIdx.x * 256 + threadIdx.x;
    if (e >= E) return;
    int s = ei[e];
    int d = ei[E + e];
    int pos = atomicAdd(&cnt[d], 1);
    if (pos < BCAP) bkt[d * BCAP + pos] = s;
}

// ---------------------------------------------------------------------------
// h2[n] = relu(init[n] + sum nbr y2)   (bf16 [N,128] row-major in/out)
// ---------------------------------------------------------------------------
__global__ void gather_relu_b16(const bf16_t* __restrict__ y2, const bf16_t* __restrict__ init,
                                const int* __restrict__ cnt, const int* __restrict__ bkt,
                                bf16_t* __restrict__ h2) {
    int t = blockIdx.x * 256 + threadIdx.x;
    int n = t >> 4;
    if (n >= NN) return;
    int j = (t & 15) * 8;
    int c = cnt[n]; if (c > BCAP) c = BCAP;
    const int* bp = bkt + n * BCAP;
    U4 u; u.v = *(const uint4*)(init + n * 128 + j);
    float s[8];
    #pragma unroll
    for (int k = 0; k < 8; ++k) s[k] = us2f(u.s[k]);
    for (int i = 0; i < c; ++i) {
        U4 w; w.v = *(const uint4*)(y2 + (size_t)bp[i] * 128 + j);
        #pragma unroll
        for (int k = 0; k < 8; ++k) s[k] += us2f(w.s[k]);
    }
    alignas(16) bf16_t ob[8];
    #pragma unroll
    for (int k = 0; k < 8; ++k) ob[k] = f2b(fmaxf(s[k], 0.f));
    *(uint4*)(h2 + n * 128 + j) = *(const uint4*)ob;
}

// outF[n] += sum nbr y4   (f32 [N,64] row-major, in-place on d_out)
__global__ void gather_add_f32_64(const float* __restrict__ y4, const int* __restrict__ cnt,
                                  const int* __restrict__ bkt, float* __restrict__ outF) {
    int t = blockIdx.x * 256 + threadIdx.x;
    int n = t >> 4;
    if (n >= NN) return;
    int j = (t & 15) * 4;
    int c = cnt[n]; if (c > BCAP) c = BCAP;
    const int* bp = bkt + n * BCAP;
    float4 sum = *(const float4*)(outF + n * 64 + j);
    for (int i = 0; i < c; ++i) {
        float4 v = *(const float4*)(y4 + (size_t)bp[i] * 64 + j);
        sum.x += v.x; sum.y += v.y; sum.z += v.z; sum.w += v.w;
    }
    *(float4*)(outF + n * 64 + j) = sum;
}

// ---------------------------------------------------------------------------
// Fused gather + two-GEMM v8: 32x32x16 MFMA + LDS-transpose epilogue.
//   v7's direct stores from the 32x32 C-layout wrote 16-32B per 64B line
//   -> 4x WRITE + RMW FETCH amplification (rocprof: W 25->106MB, F 35->148MB).
//   v8 stages acc2(+bias) into padded LDS [node][outcol] (aliasing dead
//   A/H buffers; zero extra LDS footprint) and copies out full 256B rows
//   with 16B-contiguous line-aligned stores.
//   Block = 64 nodes (2 node-tiles of 32), 512 threads = 8 waves.
//   Stage 1: wave wn owns hcol-tile (ci*8+wn) x BOTH node tiles.
//   H chunk [64 x 256] bf16, single-buffered (32KB), frag-major.
//   Stage 2: wave (og=wn>>1, wr=wn&1): OCT2 out-tiles x node-tile wr.
// Outputs: outcol < NOUT/2 -> yout, else -> initout (+bias2).
// ---------------------------------------------------------------------------
template <int K, int NOUT, int F32OUT, int SRCF32>
__global__ __launch_bounds__(512, 4) void fused8(
    const void* __restrict__ src, const int* __restrict__ cnt,
    const int* __restrict__ bkt,
    const bf16_t* __restrict__ W1f, const float* __restrict__ bias1,
    const bf16_t* __restrict__ W2f, const float* __restrict__ bias2,
    void* __restrict__ yout, void* __restrict__ initout)
{
    constexpr int KT16 = K / 16;      // A k-tiles (16-deep)
    constexpr int OT32 = NOUT / 32;   // out 32-col tiles (4 or 8)
    constexpr int OCT2 = OT32 / 4;    // out tiles per wave (1 or 2)
    constexpr int OH   = NOUT / 2;
    constexpr int SW   = K / 2;       // source row width (64 f32 / 128 bf16)
    constexpr int HALF = K / 16;      // 8-col groups per half (8 or 16)
    // epilogue staging row stride (elements): keeps 16B alignment, 4-bank row shift
    constexpr int STR  = F32OUT ? (NOUT + 4) : (NOUT + 8);
    __shared__ float b1sl[1024];
    __shared__ float b2sl[128];
    __shared__ __align__(16) char smem[(size_t)64 * K * 2 + 64 * 256 * 2];
    bf16_t* Asl = (bf16_t*)smem;                       // frag-major A tile [64*K]
    bf16_t* Hsl = (bf16_t*)(smem + (size_t)64 * K * 2); // frag-major H chunk [64*256]

    const int tid  = threadIdx.x;
    const int lane = tid & 63;
    const int wn   = tid >> 6;        // 0..7
    const int l31  = lane & 31;
    const int hi   = lane >> 5;
    const int og   = wn >> 1;         // stage-2 out-col group 0..3
    const int wr   = wn & 1;          // stage-2 node-tile 0..1
    const int bm0  = blockIdx.x * 64;

    for (int i = tid; i < 1024; i += 512) b1sl[i] = (i < 1000) ? bias1[i] : 0.f;
    if (tid < OH) b2sl[tid] = bias2[tid];

    // ---- prologue: gather + own-copy directly into Asl (frag-major)
    // tasks [0, 64*HALF): gather-sum slot; [64*HALF, 2*64*HALF): own-copy.
    #pragma unroll
    for (int it = 0; it < (2 * 64 * HALF) / 512; ++it) {
        int task = it * 512 + tid;
        const bool own = task >= 64 * HALF;
        int t2 = own ? task - 64 * HALF : task;
        int i = t2 / HALF, s = t2 - (t2 / HALF) * HALF;
        int n = bm0 + i;
        int j = s * 8;
        float sum[8] = {0.f, 0.f, 0.f, 0.f, 0.f, 0.f, 0.f, 0.f};
        if (n < NN) {
            if (!own) {
                int c = cnt[n]; if (c > BCAP) c = BCAP;
                const int* bp = bkt + n * BCAP;
                for (int e = 0; e < c; ++e) {
                    int sn = bp[e];
                    if (SRCF32) {
                        const float* r = (const float*)src + (size_t)sn * SW + j;
                        float4 a = *(const float4*)r;
                        float4 b = *(const float4*)(r + 4);
                        sum[0] += a.x; sum[1] += a.y; sum[2] += a.z; sum[3] += a.w;
                        sum[4] += b.x; sum[5] += b.y; sum[6] += b.z; sum[7] += b.w;
                    } else {
                        U4 w; w.v = *(const uint4*)((const bf16_t*)src + (size_t)sn * SW + j);
                        #pragma unroll
                        for (int k = 0; k < 8; ++k) sum[k] += us2f(w.s[k]);
                    }
                }
            } else {
                if (SRCF32) {
                    const float* r = (const float*)src + (size_t)n * SW + j;
                    float4 a = *(const float4*)r;
                    float4 b = *(const float4*)(r + 4);
                    sum[0] = a.x; sum[1] = a.y; sum[2] = a.z; sum[3] = a.w;
                    sum[4] = b.x; sum[5] = b.y; sum[6] = b.z; sum[7] = b.w;
                } else {
                    U4 w; w.v = *(const uint4*)((const bf16_t*)src + (size_t)n * SW + j);
                    #pragma unroll
                    for (int k = 0; k < 8; ++k) sum[k] = us2f(w.s[k]);
                }
            }
        }
        int cc = (own ? K / 2 : 0) + j;           // column in A's K-space
        int off = (((i >> 5) * KT16 + (cc >> 4)) * 64 + ((cc >> 3) & 1) * 32 + (i & 31)) * 8;
        alignas(16) bf16_t ob[8];
        #pragma unroll
        for (int k = 0; k < 8; ++k) ob[k] = f2b(sum[k]);
        *(uint4*)(&Asl[off]) = *(const uint4*)ob;
    }

    floatx16 acc2[OCT2];
    #pragma unroll
    for (int oo = 0; oo < OCT2; ++oo) acc2[oo] = (floatx16)FZ16;

    __syncthreads();   // Asl + biases ready

    for (int ci = 0; ci < 4; ++ci) {
        // ---- stage 1: wave computes h-tile (ci*8 + wn) x both node-tiles
        floatx16 acc1[2];
        acc1[0] = (floatx16)FZ16;
        acc1[1] = (floatx16)FZ16;

        #pragma unroll
        for (int kh = 0; kh < KT16 / 8; ++kh) {
            short8 w1v[8];
            #pragma unroll
            for (int jj = 0; jj < 8; ++jj)
                w1v[jj] = *(const short8*)(W1f + (((size_t)(ci * 8 + wn) * KT16 + kh * 8 + jj) * 64 + lane) * 8);
            #pragma unroll
            for (int jj = 0; jj < 8; ++jj) {
                #pragma unroll
                for (int nt2 = 0; nt2 < 2; ++nt2) {
                    short8 av = *(const short8*)&Asl[((nt2 * KT16 + kh * 8 + jj) * 64 + lane) * 8];
                    acc1[nt2] = __builtin_amdgcn_mfma_f32_32x32x16_bf16(w1v[jj], av, acc1[nt2], 0, 0, 0);
                }
            }
        }

        __syncthreads();   // previous chunk's stage-2 readers done with Hsl

        // bias+relu -> frag-major H; C/D: node=l31, hcol32=(r&3)+8*(r>>2)+4*hi
        #pragma unroll
        for (int nt2 = 0; nt2 < 2; ++nt2) {
            #pragma unroll
            for (int g = 0; g < 4; ++g) {
                float4 bv = *(const float4*)&b1sl[ci * 256 + wn * 32 + 8 * g + 4 * hi];
                const float* bvp = (const float*)&bv;
                alignas(8) bf16_t hb[4];
                #pragma unroll
                for (int e = 0; e < 4; ++e)
                    hb[e] = f2b(fmaxf(acc1[nt2][4 * g + e] + bvp[e], 0.f));
                int off = ((nt2 * 16 + wn * 2 + (g >> 1)) * 64 + (g & 1) * 32 + l31) * 8 + 4 * hi;
                *(uint2*)&Hsl[off] = *(const uint2*)hb;
            }
        }

        __syncthreads();   // H chunk visible

        // ---- stage 2: acc2[oo] += W2(out-tile og*OCT2+oo) x H(node-tile wr)
        #pragma unroll
        for (int ks = 0; ks < 16; ++ks) {
            short8 hf = *(const short8*)&Hsl[((wr * 16 + ks) * 64 + lane) * 8];
            #pragma unroll
            for (int oo = 0; oo < OCT2; ++oo) {
                short8 w2v = *(const short8*)(W2f + (((size_t)(og * OCT2 + oo) * 64 + ci * 16 + ks) * 64 + lane) * 8);
                acc2[oo] = __builtin_amdgcn_mfma_f32_32x32x16_bf16(w2v, hf, acc2[oo], 0, 0, 0);
            }
        }
    }

    // ---- epilogue: stage acc2(+bias) into LDS [node][outcol] (padded),
    //      then copy full rows out with coalesced line-aligned stores.
    __syncthreads();   // everyone done reading Hsl/Asl
    {
        const int r = wr * 32 + l31;   // node row within block
        if (F32OUT) {
            float* st = (float*)smem;
            #pragma unroll
            for (int oo = 0; oo < OCT2; ++oo) {
                int o = og * OCT2 + oo;
                #pragma unroll
                for (int g = 0; g < 4; ++g) {
                    int oc = o * 32 + 8 * g + 4 * hi;   // col in NOUT space
                    const bool isInit = (oc >= OH);
                    int col = isInit ? oc - OH : oc;
                    float4 bv = isInit ? *(const float4*)&b2sl[col]
                                       : make_float4(0.f, 0.f, 0.f, 0.f);
                    const float* bvp = (const float*)&bv;
                    float v[4];
                    #pragma unroll
                    for (int e = 0; e < 4; ++e) v[e] = acc2[oo][4 * g + e] + bvp[e];
                    *(float4*)&st[r * STR + oc] = make_float4(v[0], v[1], v[2], v[3]);
                }
            }
        } else {
            bf16_t* st = (bf16_t*)smem;
            #pragma unroll
            for (int oo = 0; oo < OCT2; ++oo) {
                int o = og * OCT2 + oo;
                #pragma unroll
                for (int g = 0; g < 4; ++g) {
                    int oc = o * 32 + 8 * g + 4 * hi;
                    const bool isInit = (oc >= OH);
                    int col = isInit ? oc - OH : oc;
                    float4 bv = isInit ? *(const float4*)&b2sl[col]
                                       : make_float4(0.f, 0.f, 0.f, 0.f);
                    const float* bvp = (const float*)&bv;
                    alignas(8) bf16_t ob[4];
                    #pragma unroll
                    for (int e = 0; e < 4; ++e) ob[e] = f2b(acc2[oo][4 * g + e] + bvp[e]);
                    *(uint2*)&st[r * STR + oc] = *(const uint2*)ob;
                }
            }
        }
    }
    __syncthreads();
    {
        // 16B chunks per node: f32 NOUT*4/16, bf16 NOUT*2/16 -> both 32.
        constexpr int CH = F32OUT ? (NOUT / 4) : (NOUT / 8);
        constexpr int CHH = CH / 2;    // chunks per half-row
        for (int t = tid; t < 64 * CH; t += 512) {
            int nd = t / CH, c = t - (t / CH) * CH;
            int node = bm0 + nd;
            if (node >= NN) continue;
            const bool isInit = (c >= CHH);
            int ch = isInit ? c - CHH : c;
            if (F32OUT) {
                const float* st = (const float*)smem;
                float4 v = *(const float4*)&st[nd * STR + c * 4];
                float* dst = isInit ? (float*)initout : (float*)yout;
                *(float4*)(dst + (size_t)node * OH + ch * 4) = v;
            } else {
                const bf16_t* st = (const bf16_t*)smem;
                uint4 v = *(const uint4*)&st[nd * STR + c * 8];
                bf16_t* dst = isInit ? (bf16_t*)initout : (bf16_t*)yout;
                *(uint4*)(dst + (size_t)node * OH + ch * 8) = v;
            }
        }
    }
}

// ---------------------------------------------------------------------------
// Weight packers -> 32x32x16 fragment-major bf16 (tiny, every call)
// ---------------------------------------------------------------------------
__global__ void pack_w1_frag(const float* __restrict__ Wa, const float* __restrict__ Wb,
                             bf16_t* __restrict__ out, int K1, int K2, int total) {
    int idx = blockIdx.x * 256 + threadIdx.x;
    if (idx >= total) return;
    int K = K1 + K2;
    int KT16 = K >> 4;
    int e = idx & 7;
    int l = (idx >> 3) & 63;
    int tile = idx >> 9;
    int kt = tile % KT16, t = tile / KT16;
    int c = t * 32 + (l & 31);
    int k = kt * 16 + (l >> 5) * 8 + e;
    float v = 0.f;
    if (c < 1000) v = (k < K1) ? Wa[c * K1 + k] : Wb[c * K2 + (k - K1)];
    out[idx] = f2b(v);
}
__global__ void pack_w2_frag(const float* __restrict__ Wa, const float* __restrict__ Wb,
                             bf16_t* __restrict__ out, int OH, int total) {
    int idx = blockIdx.x * 256 + threadIdx.x;
    if (idx >= total) return;
    int e = idx & 7;
    int l = (idx >> 3) & 63;
    int tile = idx >> 9;
    int kt2 = tile & 63, o = tile >> 6;   // KT2TOT = 1024/16 = 64
    int c = o * 32 + (l & 31);
    int k = kt2 * 16 + (l >> 5) * 8 + e;
    float v = 0.f;
    if (k < 1000) v = (c < OH) ? Wa[c * 1000 + k] : Wb[(c - OH) * 1000 + k];
    out[idx] = f2b(v);
}

// ---------------------------------------------------------------------------
// Mean-pool per graph (batch sorted; binary search), h2 bf16
// ---------------------------------------------------------------------------
__global__ void pool_kernel(const bf16_t* __restrict__ h2,
                            const int* __restrict__ batch,
                            float* __restrict__ enc, int Nn) {
    int g = blockIdx.x;
    __shared__ int s_lo, s_hi;
    if (threadIdx.x == 0) {
        int lo = 0, hi = Nn;
        while (lo < hi) { int mid = (lo + hi) >> 1; if (batch[mid] < g) lo = mid + 1; else hi = mid; }
        s_lo = lo;
        hi = Nn;
        while (lo < hi) { int mid = (lo + hi) >> 1; if (batch[mid] < g + 1) lo = mid + 1; else hi = mid; }
        s_hi = lo;
    }
    __syncthreads();
    int f = threadIdx.x;
    float sum = 0.f;
    for (int n = s_lo; n < s_hi; ++n) sum += b2f(h2[n * 128 + f]);
    float cnt = (float)((s_hi - s_lo) > 0 ? (s_hi - s_lo) : 1);
    enc[g * 128 + f] = sum / cnt;
}

// ---------------------------------------------------------------------------
// Launch
// ---------------------------------------------------------------------------
extern "C" void kernel_launch(void* const* d_in, const int* in_sizes, int n_in,
                              void* d_out, int out_size, void* d_ws, size_t ws_size,
                              hipStream_t stream) {
    const float* x       = (const float*)d_in[0];
    const int*   ei      = (const int*)d_in[1];
    const int*   batch   = (const int*)d_in[2];
    const float* W1_rel  = (const float*)d_in[3];
    const float* b1      = (const float*)d_in[4];
    const float* W1_root = (const float*)d_in[5];
    const float* W2_rel  = (const float*)d_in[6];
    const float* b2      = (const float*)d_in[7];
    const float* W2_root = (const float*)d_in[8];
    const float* W3_rel  = (const float*)d_in[9];
    const float* b3      = (const float*)d_in[10];
    const float* W3_root = (const float*)d_in[11];
    const float* W4_rel  = (const float*)d_in[12];
    const float* b4      = (const float*)d_in[13];
    const float* W4_root = (const float*)d_in[14];

    float* outF = (float*)d_out;            // [N,64] then [G,128]
    float* enc  = outF + NN * 64;

    char* ws = (char*)d_ws;                         // ~66 MB
    bf16_t* y2buf  = (bf16_t*)(ws + 0);             // [N,128] bf16
    bf16_t* h2init = (bf16_t*)(ws + 12800000ULL);   // [N,128] bf16
    bf16_t* h2buf  = (bf16_t*)(ws + 25600000ULL);   // [N,128] bf16
    float*  y4buf  = (float*)(ws + 38400000ULL);    // [N,64] f32
    int*    cnt    = (int*)(ws + 51200000ULL);      // [N]
    int*    bkt    = (int*)(ws + 51400064ULL);      // [N*64]
    bf16_t* W1f    = (bf16_t*)(ws + 64200064ULL);   // 1024x128 frag-major
    bf16_t* W2f    = (bf16_t*)(ws + 64462208ULL);   // 256x1024 frag-major
    bf16_t* W3f    = (bf16_t*)(ws + 64986496ULL);   // 1024x256 frag-major
    bf16_t* W4f    = (bf16_t*)(ws + 65510784ULL);   // 128x1024 frag-major

    const int RB64 = (NN + 63) / 64;  // 782

    // ---- inverted adjacency (once; reused by all 4 propagations)
    hipMemsetAsync(cnt, 0, NN * sizeof(int), stream);
    build_buckets<<<(EE + 255) / 256, 256, 0, stream>>>(ei, cnt, bkt, EE);

    // ---- pack weights to fragment-major bf16
    pack_w1_frag<<<(1024 * 128) / 256, 256, 0, stream>>>(W1_rel, W1_root, W1f, 64, 64, 1024 * 128);
    pack_w2_frag<<<(256 * 1024) / 256, 256, 0, stream>>>(W2_rel, W2_root, W2f, 128, 256 * 1024);
    pack_w1_frag<<<(1024 * 256) / 256, 256, 0, stream>>>(W3_rel, W3_root, W3f, 128, 128, 1024 * 256);
    pack_w2_frag<<<(128 * 1024) / 256, 256, 0, stream>>>(W4_rel, W4_root, W4f, 64, 128 * 1024);

    // ---- L1+L2 fused (gather in-prologue): A=[gather(x)|x]; h1 on-chip;
    //      y2 = h1@W2_rel^T (bf16), h2init = h1@W2_root^T + b2 (bf16)
    fused8<128, 256, 0, 1><<<RB64, 512, 0, stream>>>(x, cnt, bkt, W1f, b1, W2f, b2, y2buf, h2init);

    // ---- h2 = relu(h2init + gather(y2));  encoded = mean-pool(h2)
    gather_relu_b16<<<(NN * 16 + 255) / 256, 256, 0, stream>>>(y2buf, h2init, cnt, bkt, h2buf);
    pool_kernel<<<GG, 128, 0, stream>>>(h2buf, batch, enc, NN);

    // ---- L3+L4 fused (gather in-prologue): A=[gather(h2)|h2]; h3 on-chip;
    //      y4 = h3@W4_rel^T (f32), outF = h3@W4_root^T + b4 (f32, direct)
    fused8<256, 128, 1, 0><<<RB64, 512, 0, stream>>>(h2buf, cnt, bkt, W3f, b3, W4f, b4, y4buf, outF);

    // ---- out = outF + gather(y4)
    gather_add_f32_64<<<(NN * 16 + 255) / 256, 256, 0, stream>>>(y4buf, cnt, bkt, outF);
}

// Round 3
// 308.427 us; speedup vs baseline: 1.3714x; 1.3491x over previous
//
#include <hip/hip_runtime.h>
#include <hip/hip_bf16.h>

typedef __hip_bfloat16 bf16_t;
typedef __attribute__((ext_vector_type(8))) short short8;
typedef __attribute__((ext_vector_type(16))) float floatx16;

static __device__ __forceinline__ float b2f(bf16_t v) { return __bfloat162float(v); }
static __device__ __forceinline__ bf16_t f2b(float v) { return __float2bfloat16(v); }
static __device__ __forceinline__ float us2f(unsigned short u) {
    union { unsigned int i; float f; } c; c.i = ((unsigned int)u) << 16; return c.f;
}

// Problem constants
#define NN 50000
#define EE 200000
#define GG 2048
#define BCAP 64   // in-degree cap; mean deg = 4

union U4 { uint4 v; unsigned short s[8]; };

#define FZ16 {0.f,0.f,0.f,0.f,0.f,0.f,0.f,0.f,0.f,0.f,0.f,0.f,0.f,0.f,0.f,0.f}

// 32x32x16 fragment-major layout (A and B operands share it):
//   element (i, k) of an [I x K] K-major matrix lives at
//   ((i/32 * (K/16) + k/16) * 64 + ((k%16)/8)*32 + i%32) * 8 + k%8
// One wave fragment = 64 lanes x short8 = contiguous 1KB.

// ---------------------------------------------------------------------------
// Inverted adjacency build
// ---------------------------------------------------------------------------
__global__ void build_buckets(const int* __restrict__ ei, int* __restrict__ cnt,
                              int* __restrict__ bkt, int E) {
    int e = blockIdx.x * 256 + threadIdx.x;
    if (e >= E) return;
    int s = ei[e];
    int d = ei[E + e];
    int pos = atomicAdd(&cnt[d], 1);
    if (pos < BCAP) bkt[d * BCAP + pos] = s;
}

// ---------------------------------------------------------------------------
// h2[n] = relu(init[n] + sum nbr y2)   (bf16 [N,128] row-major in/out)
// ---------------------------------------------------------------------------
__global__ void gather_relu_b16(const bf16_t* __restrict__ y2, const bf16_t* __restrict__ init,
                                const int* __restrict__ cnt, const int* __restrict__ bkt,
                                bf16_t* __restrict__ h2) {
    int t = blockIdx.x * 256 + threadIdx.x;
    int n = t >> 4;
    if (n >= NN) return;
    int j = (t & 15) * 8;
    int c = cnt[n]; if (c > BCAP) c = BCAP;
    const int* bp = bkt + n * BCAP;
    U4 u; u.v = *(const uint4*)(init + n * 128 + j);
    float s[8];
    #pragma unroll
    for (int k = 0; k < 8; ++k) s[k] = us2f(u.s[k]);
    for (int i = 0; i < c; ++i) {
        U4 w; w.v = *(const uint4*)(y2 + (size_t)bp[i] * 128 + j);
        #pragma unroll
        for (int k = 0; k < 8; ++k) s[k] += us2f(w.s[k]);
    }
    alignas(16) bf16_t ob[8];
    #pragma unroll
    for (int k = 0; k < 8; ++k) ob[k] = f2b(fmaxf(s[k], 0.f));
    *(uint4*)(h2 + n * 128 + j) = *(const uint4*)ob;
}

// outF[n] += sum nbr y4   (f32 [N,64] row-major, in-place on d_out)
__global__ void gather_add_f32_64(const float* __restrict__ y4, const int* __restrict__ cnt,
                                  const int* __restrict__ bkt, float* __restrict__ outF) {
    int t = blockIdx.x * 256 + threadIdx.x;
    int n = t >> 4;
    if (n >= NN) return;
    int j = (t & 15) * 4;
    int c = cnt[n]; if (c > BCAP) c = BCAP;
    const int* bp = bkt + n * BCAP;
    float4 sum = *(const float4*)(outF + n * 64 + j);
    for (int i = 0; i < c; ++i) {
        float4 v = *(const float4*)(y4 + (size_t)bp[i] * 64 + j);
        sum.x += v.x; sum.y += v.y; sum.z += v.z; sum.w += v.w;
    }
    *(float4*)(outF + n * 64 + j) = sum;
}

// ---------------------------------------------------------------------------
// Fused gather + two-GEMM v9: 32x32x16 MFMA, LDS-transpose epilogue,
// REGISTER-PRESSURE FIX: v7/v8 spilled accumulators to scratch
// (__launch_bounds__(512,4) caps unified VGPRs at 128; acc1+acc2=64 plus
// w1v[8] prefetch array blew the budget -> ~82MB scratch writes +
// ~114MB reads per dispatch, visible as WRITE_SIZE 108MB / FETCH 149MB).
// v9 uses rolling single-fragment weight loads (w1/w2 loaded just before
// each MFMA, unroll capped at 2) so peak live set ~= 64 acc + ~35 arch.
//   Block = 64 nodes (2 node-tiles of 32), 512 threads = 8 waves.
//   Stage 1: wave wn owns hcol-tile (ci*8+wn) x BOTH node tiles.
//   H chunk [64 x 256] bf16, single-buffered (32KB), frag-major.
//   Stage 2: wave (og=wn>>1, wr=wn&1): OCT2 out-tiles x node-tile wr.
// Outputs: outcol < NOUT/2 -> yout, else -> initout (+bias2).
// ---------------------------------------------------------------------------
template <int K, int NOUT, int F32OUT, int SRCF32>
__global__ __launch_bounds__(512, 4) void fused9(
    const void* __restrict__ src, const int* __restrict__ cnt,
    const int* __restrict__ bkt,
    const bf16_t* __restrict__ W1f, const float* __restrict__ bias1,
    const bf16_t* __restrict__ W2f, const float* __restrict__ bias2,
    void* __restrict__ yout, void* __restrict__ initout)
{
    constexpr int KT16 = K / 16;      // A k-tiles (16-deep)
    constexpr int OT32 = NOUT / 32;   // out 32-col tiles (4 or 8)
    constexpr int OCT2 = OT32 / 4;    // out tiles per wave (1 or 2)
    constexpr int OH   = NOUT / 2;
    constexpr int SW   = K / 2;       // source row width (64 f32 / 128 bf16)
    constexpr int HALF = K / 16;      // 8-col groups per half (8 or 16)
    // epilogue staging row stride (elements): keeps 16B alignment, 4-bank row shift
    constexpr int STR  = F32OUT ? (NOUT + 4) : (NOUT + 8);
    __shared__ float b1sl[1024];
    __shared__ float b2sl[128];
    __shared__ __align__(16) char smem[(size_t)64 * K * 2 + 64 * 256 * 2];
    bf16_t* Asl = (bf16_t*)smem;                       // frag-major A tile [64*K]
    bf16_t* Hsl = (bf16_t*)(smem + (size_t)64 * K * 2); // frag-major H chunk [64*256]

    const int tid  = threadIdx.x;
    const int lane = tid & 63;
    const int wn   = tid >> 6;        // 0..7
    const int l31  = lane & 31;
    const int hi   = lane >> 5;
    const int og   = wn >> 1;         // stage-2 out-col group 0..3
    const int wr   = wn & 1;          // stage-2 node-tile 0..1
    const int bm0  = blockIdx.x * 64;

    for (int i = tid; i < 1024; i += 512) b1sl[i] = (i < 1000) ? bias1[i] : 0.f;
    if (tid < OH) b2sl[tid] = bias2[tid];

    // ---- prologue: gather + own-copy directly into Asl (frag-major)
    // tasks [0, 64*HALF): gather-sum slot; [64*HALF, 2*64*HALF): own-copy.
    #pragma unroll
    for (int it = 0; it < (2 * 64 * HALF) / 512; ++it) {
        int task = it * 512 + tid;
        const bool own = task >= 64 * HALF;
        int t2 = own ? task - 64 * HALF : task;
        int i = t2 / HALF, s = t2 - (t2 / HALF) * HALF;
        int n = bm0 + i;
        int j = s * 8;
        float sum[8] = {0.f, 0.f, 0.f, 0.f, 0.f, 0.f, 0.f, 0.f};
        if (n < NN) {
            if (!own) {
                int c = cnt[n]; if (c > BCAP) c = BCAP;
                const int* bp = bkt + n * BCAP;
                for (int e = 0; e < c; ++e) {
                    int sn = bp[e];
                    if (SRCF32) {
                        const float* r = (const float*)src + (size_t)sn * SW + j;
                        float4 a = *(const float4*)r;
                        float4 b = *(const float4*)(r + 4);
                        sum[0] += a.x; sum[1] += a.y; sum[2] += a.z; sum[3] += a.w;
                        sum[4] += b.x; sum[5] += b.y; sum[6] += b.z; sum[7] += b.w;
                    } else {
                        U4 w; w.v = *(const uint4*)((const bf16_t*)src + (size_t)sn * SW + j);
                        #pragma unroll
                        for (int k = 0; k < 8; ++k) sum[k] += us2f(w.s[k]);
                    }
                }
            } else {
                if (SRCF32) {
                    const float* r = (const float*)src + (size_t)n * SW + j;
                    float4 a = *(const float4*)r;
                    float4 b = *(const float4*)(r + 4);
                    sum[0] = a.x; sum[1] = a.y; sum[2] = a.z; sum[3] = a.w;
                    sum[4] = b.x; sum[5] = b.y; sum[6] = b.z; sum[7] = b.w;
                } else {
                    U4 w; w.v = *(const uint4*)((const bf16_t*)src + (size_t)n * SW + j);
                    #pragma unroll
                    for (int k = 0; k < 8; ++k) sum[k] = us2f(w.s[k]);
                }
            }
        }
        int cc = (own ? K / 2 : 0) + j;           // column in A's K-space
        int off = (((i >> 5) * KT16 + (cc >> 4)) * 64 + ((cc >> 3) & 1) * 32 + (i & 31)) * 8;
        alignas(16) bf16_t ob[8];
        #pragma unroll
        for (int k = 0; k < 8; ++k) ob[k] = f2b(sum[k]);
        *(uint4*)(&Asl[off]) = *(const uint4*)ob;
    }

    floatx16 acc2[OCT2];
    #pragma unroll
    for (int oo = 0; oo < OCT2; ++oo) acc2[oo] = (floatx16)FZ16;

    __syncthreads();   // Asl + biases ready

    for (int ci = 0; ci < 4; ++ci) {
        // ---- stage 1: wave computes h-tile (ci*8 + wn) x both node-tiles
        floatx16 acc1[2];
        acc1[0] = (floatx16)FZ16;
        acc1[1] = (floatx16)FZ16;

        // rolling single-fragment weight load (reg-pressure: 1 w1 + 2 av live)
        const bf16_t* w1p = W1f + (((size_t)(ci * 8 + wn) * KT16) * 64 + lane) * 8;
        #pragma unroll 2
        for (int kk = 0; kk < KT16; ++kk) {
            short8 w1 = *(const short8*)(w1p + (size_t)kk * 64 * 8);
            short8 av0 = *(const short8*)&Asl[((0 * KT16 + kk) * 64 + lane) * 8];
            acc1[0] = __builtin_amdgcn_mfma_f32_32x32x16_bf16(w1, av0, acc1[0], 0, 0, 0);
            short8 av1 = *(const short8*)&Asl[((1 * KT16 + kk) * 64 + lane) * 8];
            acc1[1] = __builtin_amdgcn_mfma_f32_32x32x16_bf16(w1, av1, acc1[1], 0, 0, 0);
        }

        __syncthreads();   // previous chunk's stage-2 readers done with Hsl

        // bias+relu -> frag-major H; C/D: node=l31, hcol32=(r&3)+8*(r>>2)+4*hi
        #pragma unroll
        for (int nt2 = 0; nt2 < 2; ++nt2) {
            #pragma unroll
            for (int g = 0; g < 4; ++g) {
                float4 bv = *(const float4*)&b1sl[ci * 256 + wn * 32 + 8 * g + 4 * hi];
                const float* bvp = (const float*)&bv;
                alignas(8) bf16_t hb[4];
                #pragma unroll
                for (int e = 0; e < 4; ++e)
                    hb[e] = f2b(fmaxf(acc1[nt2][4 * g + e] + bvp[e], 0.f));
                int off = ((nt2 * 16 + wn * 2 + (g >> 1)) * 64 + (g & 1) * 32 + l31) * 8 + 4 * hi;
                *(uint2*)&Hsl[off] = *(const uint2*)hb;
            }
        }

        __syncthreads();   // H chunk visible

        // ---- stage 2: acc2[oo] += W2(out-tile og*OCT2+oo) x H(node-tile wr)
        const bf16_t* w2p = W2f + ((((size_t)(og * OCT2)) * 64 + ci * 16) * 64 + lane) * 8;
        #pragma unroll 2
        for (int ks = 0; ks < 16; ++ks) {
            short8 hf = *(const short8*)&Hsl[((wr * 16 + ks) * 64 + lane) * 8];
            #pragma unroll
            for (int oo = 0; oo < OCT2; ++oo) {
                short8 w2v = *(const short8*)(w2p + ((size_t)oo * 64 + ks) * 64 * 8);
                acc2[oo] = __builtin_amdgcn_mfma_f32_32x32x16_bf16(w2v, hf, acc2[oo], 0, 0, 0);
            }
        }
    }

    // ---- epilogue: stage acc2(+bias) into LDS [node][outcol] (padded),
    //      then copy full rows out with coalesced line-aligned stores.
    __syncthreads();   // everyone done reading Hsl/Asl
    {
        const int r = wr * 32 + l31;   // node row within block
        if (F32OUT) {
            float* st = (float*)smem;
            #pragma unroll
            for (int oo = 0; oo < OCT2; ++oo) {
                int o = og * OCT2 + oo;
                #pragma unroll
                for (int g = 0; g < 4; ++g) {
                    int oc = o * 32 + 8 * g + 4 * hi;   // col in NOUT space
                    const bool isInit = (oc >= OH);
                    int col = isInit ? oc - OH : oc;
                    float4 bv = isInit ? *(const float4*)&b2sl[col]
                                       : make_float4(0.f, 0.f, 0.f, 0.f);
                    const float* bvp = (const float*)&bv;
                    float v[4];
                    #pragma unroll
                    for (int e = 0; e < 4; ++e) v[e] = acc2[oo][4 * g + e] + bvp[e];
                    *(float4*)&st[r * STR + oc] = make_float4(v[0], v[1], v[2], v[3]);
                }
            }
        } else {
            bf16_t* st = (bf16_t*)smem;
            #pragma unroll
            for (int oo = 0; oo < OCT2; ++oo) {
                int o = og * OCT2 + oo;
                #pragma unroll
                for (int g = 0; g < 4; ++g) {
                    int oc = o * 32 + 8 * g + 4 * hi;
                    const bool isInit = (oc >= OH);
                    int col = isInit ? oc - OH : oc;
                    float4 bv = isInit ? *(const float4*)&b2sl[col]
                                       : make_float4(0.f, 0.f, 0.f, 0.f);
                    const float* bvp = (const float*)&bv;
                    alignas(8) bf16_t ob[4];
                    #pragma unroll
                    for (int e = 0; e < 4; ++e) ob[e] = f2b(acc2[oo][4 * g + e] + bvp[e]);
                    *(uint2*)&st[r * STR + oc] = *(const uint2*)ob;
                }
            }
        }
    }
    __syncthreads();
    {
        // 16B chunks per node: f32 NOUT*4/16, bf16 NOUT*2/16 -> both 32.
        constexpr int CH = F32OUT ? (NOUT / 4) : (NOUT / 8);
        constexpr int CHH = CH / 2;    // chunks per half-row
        for (int t = tid; t < 64 * CH; t += 512) {
            int nd = t / CH, c = t - (t / CH) * CH;
            int node = bm0 + nd;
            if (node >= NN) continue;
            const bool isInit = (c >= CHH);
            int ch = isInit ? c - CHH : c;
            if (F32OUT) {
                const float* st = (const float*)smem;
                float4 v = *(const float4*)&st[nd * STR + c * 4];
                float* dst = isInit ? (float*)initout : (float*)yout;
                *(float4*)(dst + (size_t)node * OH + ch * 4) = v;
            } else {
                const bf16_t* st = (const bf16_t*)smem;
                uint4 v = *(const uint4*)&st[nd * STR + c * 8];
                bf16_t* dst = isInit ? (bf16_t*)initout : (bf16_t*)yout;
                *(uint4*)(dst + (size_t)node * OH + ch * 8) = v;
            }
        }
    }
}

// ---------------------------------------------------------------------------
// Weight packers -> 32x32x16 fragment-major bf16 (tiny, every call)
// ---------------------------------------------------------------------------
__global__ void pack_w1_frag(const float* __restrict__ Wa, const float* __restrict__ Wb,
                             bf16_t* __restrict__ out, int K1, int K2, int total) {
    int idx = blockIdx.x * 256 + threadIdx.x;
    if (idx >= total) return;
    int K = K1 + K2;
    int KT16 = K >> 4;
    int e = idx & 7;
    int l = (idx >> 3) & 63;
    int tile = idx >> 9;
    int kt = tile % KT16, t = tile / KT16;
    int c = t * 32 + (l & 31);
    int k = kt * 16 + (l >> 5) * 8 + e;
    float v = 0.f;
    if (c < 1000) v = (k < K1) ? Wa[c * K1 + k] : Wb[c * K2 + (k - K1)];
    out[idx] = f2b(v);
}
__global__ void pack_w2_frag(const float* __restrict__ Wa, const float* __restrict__ Wb,
                             bf16_t* __restrict__ out, int OH, int total) {
    int idx = blockIdx.x * 256 + threadIdx.x;
    if (idx >= total) return;
    int e = idx & 7;
    int l = (idx >> 3) & 63;
    int tile = idx >> 9;
    int kt2 = tile & 63, o = tile >> 6;   // KT2TOT = 1024/16 = 64
    int c = o * 32 + (l & 31);
    int k = kt2 * 16 + (l >> 5) * 8 + e;
    float v = 0.f;
    if (k < 1000) v = (c < OH) ? Wa[c * 1000 + k] : Wb[(c - OH) * 1000 + k];
    out[idx] = f2b(v);
}

// ---------------------------------------------------------------------------
// Mean-pool per graph (batch sorted; binary search), h2 bf16
// ---------------------------------------------------------------------------
__global__ void pool_kernel(const bf16_t* __restrict__ h2,
                            const int* __restrict__ batch,
                            float* __restrict__ enc, int Nn) {
    int g = blockIdx.x;
    __shared__ int s_lo, s_hi;
    if (threadIdx.x == 0) {
        int lo = 0, hi = Nn;
        while (lo < hi) { int mid = (lo + hi) >> 1; if (batch[mid] < g) lo = mid + 1; else hi = mid; }
        s_lo = lo;
        hi = Nn;
        while (lo < hi) { int mid = (lo + hi) >> 1; if (batch[mid] < g + 1) lo = mid + 1; else hi = mid; }
        s_hi = lo;
    }
    __syncthreads();
    int f = threadIdx.x;
    float sum = 0.f;
    for (int n = s_lo; n < s_hi; ++n) sum += b2f(h2[n * 128 + f]);
    float cnt = (float)((s_hi - s_lo) > 0 ? (s_hi - s_lo) : 1);
    enc[g * 128 + f] = sum / cnt;
}

// ---------------------------------------------------------------------------
// Launch
// ---------------------------------------------------------------------------
extern "C" void kernel_launch(void* const* d_in, const int* in_sizes, int n_in,
                              void* d_out, int out_size, void* d_ws, size_t ws_size,
                              hipStream_t stream) {
    const float* x       = (const float*)d_in[0];
    const int*   ei      = (const int*)d_in[1];
    const int*   batch   = (const int*)d_in[2];
    const float* W1_rel  = (const float*)d_in[3];
    const float* b1      = (const float*)d_in[4];
    const float* W1_root = (const float*)d_in[5];
    const float* W2_rel  = (const float*)d_in[6];
    const float* b2      = (const float*)d_in[7];
    const float* W2_root = (const float*)d_in[8];
    const float* W3_rel  = (const float*)d_in[9];
    const float* b3      = (const float*)d_in[10];
    const float* W3_root = (const float*)d_in[11];
    const float* W4_rel  = (const float*)d_in[12];
    const float* b4      = (const float*)d_in[13];
    const float* W4_root = (const float*)d_in[14];

    float* outF = (float*)d_out;            // [N,64] then [G,128]
    float* enc  = outF + NN * 64;

    char* ws = (char*)d_ws;                         // ~66 MB
    bf16_t* y2buf  = (bf16_t*)(ws + 0);             // [N,128] bf16
    bf16_t* h2init = (bf16_t*)(ws + 12800000ULL);   // [N,128] bf16
    bf16_t* h2buf  = (bf16_t*)(ws + 25600000ULL);   // [N,128] bf16
    float*  y4buf  = (float*)(ws + 38400000ULL);    // [N,64] f32
    int*    cnt    = (int*)(ws + 51200000ULL);      // [N]
    int*    bkt    = (int*)(ws + 51400064ULL);      // [N*64]
    bf16_t* W1f    = (bf16_t*)(ws + 64200064ULL);   // 1024x128 frag-major
    bf16_t* W2f    = (bf16_t*)(ws + 64462208ULL);   // 256x1024 frag-major
    bf16_t* W3f    = (bf16_t*)(ws + 64986496ULL);   // 1024x256 frag-major
    bf16_t* W4f    = (bf16_t*)(ws + 65510784ULL);   // 128x1024 frag-major

    const int RB64 = (NN + 63) / 64;  // 782

    // ---- inverted adjacency (once; reused by all 4 propagations)
    hipMemsetAsync(cnt, 0, NN * sizeof(int), stream);
    build_buckets<<<(EE + 255) / 256, 256, 0, stream>>>(ei, cnt, bkt, EE);

    // ---- pack weights to fragment-major bf16
    pack_w1_frag<<<(1024 * 128) / 256, 256, 0, stream>>>(W1_rel, W1_root, W1f, 64, 64, 1024 * 128);
    pack_w2_frag<<<(256 * 1024) / 256, 256, 0, stream>>>(W2_rel, W2_root, W2f, 128, 256 * 1024);
    pack_w1_frag<<<(1024 * 256) / 256, 256, 0, stream>>>(W3_rel, W3_root, W3f, 128, 128, 1024 * 256);
    pack_w2_frag<<<(128 * 1024) / 256, 256, 0, stream>>>(W4_rel, W4_root, W4f, 64, 128 * 1024);

    // ---- L1+L2 fused (gather in-prologue): A=[gather(x)|x]; h1 on-chip;
    //      y2 = h1@W2_rel^T (bf16), h2init = h1@W2_root^T + b2 (bf16)
    fused9<128, 256, 0, 1><<<RB64, 512, 0, stream>>>(x, cnt, bkt, W1f, b1, W2f, b2, y2buf, h2init);

    // ---- h2 = relu(h2init + gather(y2));  encoded = mean-pool(h2)
    gather_relu_b16<<<(NN * 16 + 255) / 256, 256, 0, stream>>>(y2buf, h2init, cnt, bkt, h2buf);
    pool_kernel<<<GG, 128, 0, stream>>>(h2buf, batch, enc, NN);

    // ---- L3+L4 fused (gather in-prologue): A=[gather(h2)|h2]; h3 on-chip;
    //      y4 = h3@W4_rel^T (f32), outF = h3@W4_root^T + b4 (f32, direct)
    fused9<256, 128, 1, 0><<<RB64, 512, 0, stream>>>(h2buf, cnt, bkt, W3f, b3, W4f, b4, y4buf, outF);

    // ---- out = outF + gather(y4)
    gather_add_f32_64<<<(NN * 16 + 255) / 256, 256, 0, stream>>>(y4buf, cnt, bkt, outF);
}

// Round 4
// 304.337 us; speedup vs baseline: 1.3898x; 1.0134x over previous
//
#include <hip/hip_runtime.h>
#include <hip/hip_bf16.h>

typedef __hip_bfloat16 bf16_t;
typedef __attribute__((ext_vector_type(8))) short short8;
typedef __attribute__((ext_vector_type(16))) float floatx16;

static __device__ __forceinline__ float b2f(bf16_t v) { return __bfloat162float(v); }
static __device__ __forceinline__ bf16_t f2b(float v) { return __float2bfloat16(v); }
static __device__ __forceinline__ float us2f(unsigned short u) {
    union { unsigned int i; float f; } c; c.i = ((unsigned int)u) << 16; return c.f;
}

// Problem constants
#define NN 50000
#define EE 200000
#define GG 2048
#define BCAP 64   // in-degree cap; mean deg = 4

union U4 { uint4 v; unsigned short s[8]; };

#define FZ16 {0.f,0.f,0.f,0.f,0.f,0.f,0.f,0.f,0.f,0.f,0.f,0.f,0.f,0.f,0.f,0.f}

// 32x32x16 fragment-major layout (A and B operands share it):
//   element (i, k) of an [I x K] K-major matrix lives at
//   ((i/32 * (K/16) + k/16) * 64 + ((k%16)/8)*32 + i%32) * 8 + k%8
// One wave fragment = 64 lanes x short8 = contiguous 1KB.

// ---------------------------------------------------------------------------
// Merged setup: inverted adjacency build + all 4 weight packs in ONE launch
// (was 5 launches; each ~5-10us of gap). Block ranges select the job.
// ---------------------------------------------------------------------------
__device__ __forceinline__ void pack_w1_body(const float* __restrict__ Wa,
                                             const float* __restrict__ Wb,
                                             bf16_t* __restrict__ out,
                                             int K1, int K2, int idx) {
    int K = K1 + K2;
    int KT16 = K >> 4;
    int e = idx & 7;
    int l = (idx >> 3) & 63;
    int tile = idx >> 9;
    int kt = tile % KT16, t = tile / KT16;
    int c = t * 32 + (l & 31);
    int k = kt * 16 + (l >> 5) * 8 + e;
    float v = 0.f;
    if (c < 1000) v = (k < K1) ? Wa[c * K1 + k] : Wb[c * K2 + (k - K1)];
    out[idx] = f2b(v);
}
__device__ __forceinline__ void pack_w2_body(const float* __restrict__ Wa,
                                             const float* __restrict__ Wb,
                                             bf16_t* __restrict__ out,
                                             int OH, int idx) {
    int e = idx & 7;
    int l = (idx >> 3) & 63;
    int tile = idx >> 9;
    int kt2 = tile & 63, o = tile >> 6;   // K=1024 -> 64 k-tiles
    int c = o * 32 + (l & 31);
    int k = kt2 * 16 + (l >> 5) * 8 + e;
    float v = 0.f;
    if (k < 1000) v = (c < OH) ? Wa[c * 1000 + k] : Wb[(c - OH) * 1000 + k];
    out[idx] = f2b(v);
}

#define NB_BUILD 782   // (EE+255)/256
#define NB_P1 512      // 131072/256
#define NB_P2 1024     // 262144/256
#define NB_P3 1024
#define NB_P4 512

__global__ void setup_all(const int* __restrict__ ei, int* __restrict__ cnt,
                          int* __restrict__ bkt,
                          const float* __restrict__ W1_rel, const float* __restrict__ W1_root,
                          const float* __restrict__ W2_rel, const float* __restrict__ W2_root,
                          const float* __restrict__ W3_rel, const float* __restrict__ W3_root,
                          const float* __restrict__ W4_rel, const float* __restrict__ W4_root,
                          bf16_t* __restrict__ W1f, bf16_t* __restrict__ W2f,
                          bf16_t* __restrict__ W3f, bf16_t* __restrict__ W4f) {
    int b = blockIdx.x;
    int tid = threadIdx.x;
    if (b < NB_BUILD) {
        int e = b * 256 + tid;
        if (e < EE) {
            int s = ei[e];
            int d = ei[EE + e];
            int pos = atomicAdd(&cnt[d], 1);
            if (pos < BCAP) bkt[d * BCAP + pos] = s;
        }
    } else if (b < NB_BUILD + NB_P1) {
        pack_w1_body(W1_rel, W1_root, W1f, 64, 64, (b - NB_BUILD) * 256 + tid);
    } else if (b < NB_BUILD + NB_P1 + NB_P2) {
        pack_w2_body(W2_rel, W2_root, W2f, 128, (b - NB_BUILD - NB_P1) * 256 + tid);
    } else if (b < NB_BUILD + NB_P1 + NB_P2 + NB_P3) {
        pack_w1_body(W3_rel, W3_root, W3f, 128, 128, (b - NB_BUILD - NB_P1 - NB_P2) * 256 + tid);
    } else {
        pack_w2_body(W4_rel, W4_root, W4f, 64, (b - NB_BUILD - NB_P1 - NB_P2 - NB_P3) * 256 + tid);
    }
}

// ---------------------------------------------------------------------------
// h2[n] = relu(init[n] + sum nbr y2)   (bf16 [N,128] row-major in/out)
// 4-way batched neighbor loads: 4 independent row loads in flight instead of
// a serial dependent chain (mean deg = 4 -> usually one batch).
// ---------------------------------------------------------------------------
__global__ void gather_relu_b16(const bf16_t* __restrict__ y2, const bf16_t* __restrict__ init,
                                const int* __restrict__ cnt, const int* __restrict__ bkt,
                                bf16_t* __restrict__ h2) {
    int t = blockIdx.x * 256 + threadIdx.x;
    int n = t >> 4;
    if (n >= NN) return;
    int j = (t & 15) * 8;
    int c = cnt[n]; if (c > BCAP) c = BCAP;
    const int* bp = bkt + n * BCAP;
    U4 u; u.v = *(const uint4*)(init + n * 128 + j);
    float s[8];
    #pragma unroll
    for (int k = 0; k < 8; ++k) s[k] = us2f(u.s[k]);
    int i = 0;
    for (; i + 4 <= c; i += 4) {
        int s0 = bp[i], s1 = bp[i + 1], s2 = bp[i + 2], s3 = bp[i + 3];
        U4 w0, w1, w2, w3;
        w0.v = *(const uint4*)(y2 + (size_t)s0 * 128 + j);
        w1.v = *(const uint4*)(y2 + (size_t)s1 * 128 + j);
        w2.v = *(const uint4*)(y2 + (size_t)s2 * 128 + j);
        w3.v = *(const uint4*)(y2 + (size_t)s3 * 128 + j);
        #pragma unroll
        for (int k = 0; k < 8; ++k)
            s[k] += (us2f(w0.s[k]) + us2f(w1.s[k])) + (us2f(w2.s[k]) + us2f(w3.s[k]));
    }
    for (; i < c; ++i) {
        U4 w; w.v = *(const uint4*)(y2 + (size_t)bp[i] * 128 + j);
        #pragma unroll
        for (int k = 0; k < 8; ++k) s[k] += us2f(w.s[k]);
    }
    alignas(16) bf16_t ob[8];
    #pragma unroll
    for (int k = 0; k < 8; ++k) ob[k] = f2b(fmaxf(s[k], 0.f));
    *(uint4*)(h2 + n * 128 + j) = *(const uint4*)ob;
}

// outF[n] += sum nbr y4   (f32 [N,64] row-major, in-place on d_out)
__global__ void gather_add_f32_64(const float* __restrict__ y4, const int* __restrict__ cnt,
                                  const int* __restrict__ bkt, float* __restrict__ outF) {
    int t = blockIdx.x * 256 + threadIdx.x;
    int n = t >> 4;
    if (n >= NN) return;
    int j = (t & 15) * 4;
    int c = cnt[n]; if (c > BCAP) c = BCAP;
    const int* bp = bkt + n * BCAP;
    float4 sum = *(const float4*)(outF + n * 64 + j);
    int i = 0;
    for (; i + 4 <= c; i += 4) {
        int s0 = bp[i], s1 = bp[i + 1], s2 = bp[i + 2], s3 = bp[i + 3];
        float4 v0 = *(const float4*)(y4 + (size_t)s0 * 64 + j);
        float4 v1 = *(const float4*)(y4 + (size_t)s1 * 64 + j);
        float4 v2 = *(const float4*)(y4 + (size_t)s2 * 64 + j);
        float4 v3 = *(const float4*)(y4 + (size_t)s3 * 64 + j);
        sum.x += (v0.x + v1.x) + (v2.x + v3.x);
        sum.y += (v0.y + v1.y) + (v2.y + v3.y);
        sum.z += (v0.z + v1.z) + (v2.z + v3.z);
        sum.w += (v0.w + v1.w) + (v2.w + v3.w);
    }
    for (; i < c; ++i) {
        float4 v = *(const float4*)(y4 + (size_t)bp[i] * 64 + j);
        sum.x += v.x; sum.y += v.y; sum.z += v.z; sum.w += v.w;
    }
    *(float4*)(outF + n * 64 + j) = sum;
}

// ---------------------------------------------------------------------------
// Fused gather + two-GEMM v10: 32x32x16 MFMA, LDS-transpose epilogue,
// SOFTWARE-PIPELINED weight loads. v9 (VGPR=52, budget 128) had every MFMA
// waiting on a just-issued L2 weight load (~200-300cy): MfmaUtil 19%,
// VALUBusy 15%, HBM 9% -> latency-bound. v10 rotates a 1-ahead prefetch
// register for w1/w2 (unroll 4 bounds compiler hoisting to ~4 frags = 16
// VGPRs), target live set ~= 64 acc + ~35 arch < 128. Prologue gather uses
// 4-way batched neighbor loads.
//   Block = 64 nodes (2 node-tiles of 32), 512 threads = 8 waves.
//   Stage 1: wave wn owns hcol-tile (ci*8+wn) x BOTH node tiles.
//   H chunk [64 x 256] bf16, single-buffered (32KB), frag-major.
//   Stage 2: wave (og=wn>>1, wr=wn&1): OCT2 out-tiles x node-tile wr.
// Outputs: outcol < NOUT/2 -> yout, else -> initout (+bias2).
// ---------------------------------------------------------------------------
template <int K, int NOUT, int F32OUT, int SRCF32>
__global__ __launch_bounds__(512, 4) void fused10(
    const void* __restrict__ src, const int* __restrict__ cnt,
    const int* __restrict__ bkt,
    const bf16_t* __restrict__ W1f, const float* __restrict__ bias1,
    const bf16_t* __restrict__ W2f, const float* __restrict__ bias2,
    void* __restrict__ yout, void* __restrict__ initout)
{
    constexpr int KT16 = K / 16;      // A k-tiles (16-deep)
    constexpr int OT32 = NOUT / 32;   // out 32-col tiles (4 or 8)
    constexpr int OCT2 = OT32 / 4;    // out tiles per wave (1 or 2)
    constexpr int OH   = NOUT / 2;
    constexpr int SW   = K / 2;       // source row width (64 f32 / 128 bf16)
    constexpr int HALF = K / 16;      // 8-col groups per half (8 or 16)
    // epilogue staging row stride (elements): keeps 16B alignment, 4-bank row shift
    constexpr int STR  = F32OUT ? (NOUT + 4) : (NOUT + 8);
    __shared__ float b1sl[1024];
    __shared__ float b2sl[128];
    __shared__ __align__(16) char smem[(size_t)64 * K * 2 + 64 * 256 * 2];
    bf16_t* Asl = (bf16_t*)smem;                       // frag-major A tile [64*K]
    bf16_t* Hsl = (bf16_t*)(smem + (size_t)64 * K * 2); // frag-major H chunk [64*256]

    const int tid  = threadIdx.x;
    const int lane = tid & 63;
    const int wn   = tid >> 6;        // 0..7
    const int l31  = lane & 31;
    const int hi   = lane >> 5;
    const int og   = wn >> 1;         // stage-2 out-col group 0..3
    const int wr   = wn & 1;          // stage-2 node-tile 0..1
    const int bm0  = blockIdx.x * 64;

    for (int i = tid; i < 1024; i += 512) b1sl[i] = (i < 1000) ? bias1[i] : 0.f;
    if (tid < OH) b2sl[tid] = bias2[tid];

    // ---- prologue: gather + own-copy directly into Asl (frag-major)
    // tasks [0, 64*HALF): gather-sum slot; [64*HALF, 2*64*HALF): own-copy.
    #pragma unroll
    for (int it = 0; it < (2 * 64 * HALF) / 512; ++it) {
        int task = it * 512 + tid;
        const bool own = task >= 64 * HALF;
        int t2 = own ? task - 64 * HALF : task;
        int i = t2 / HALF, s = t2 - (t2 / HALF) * HALF;
        int n = bm0 + i;
        int j = s * 8;
        float sum[8] = {0.f, 0.f, 0.f, 0.f, 0.f, 0.f, 0.f, 0.f};
        if (n < NN) {
            if (!own) {
                int c = cnt[n]; if (c > BCAP) c = BCAP;
                const int* bp = bkt + n * BCAP;
                int e = 0;
                for (; e + 4 <= c; e += 4) {
                    int s0 = bp[e], s1 = bp[e + 1], s2 = bp[e + 2], s3 = bp[e + 3];
                    if (SRCF32) {
                        const float* r0 = (const float*)src + (size_t)s0 * SW + j;
                        const float* r1 = (const float*)src + (size_t)s1 * SW + j;
                        const float* r2 = (const float*)src + (size_t)s2 * SW + j;
                        const float* r3 = (const float*)src + (size_t)s3 * SW + j;
                        float4 a0 = *(const float4*)r0, b0 = *(const float4*)(r0 + 4);
                        float4 a1 = *(const float4*)r1, b1 = *(const float4*)(r1 + 4);
                        float4 a2 = *(const float4*)r2, b2 = *(const float4*)(r2 + 4);
                        float4 a3 = *(const float4*)r3, b3 = *(const float4*)(r3 + 4);
                        sum[0] += (a0.x + a1.x) + (a2.x + a3.x);
                        sum[1] += (a0.y + a1.y) + (a2.y + a3.y);
                        sum[2] += (a0.z + a1.z) + (a2.z + a3.z);
                        sum[3] += (a0.w + a1.w) + (a2.w + a3.w);
                        sum[4] += (b0.x + b1.x) + (b2.x + b3.x);
                        sum[5] += (b0.y + b1.y) + (b2.y + b3.y);
                        sum[6] += (b0.z + b1.z) + (b2.z + b3.z);
                        sum[7] += (b0.w + b1.w) + (b2.w + b3.w);
                    } else {
                        U4 w0, w1, w2, w3;
                        w0.v = *(const uint4*)((const bf16_t*)src + (size_t)s0 * SW + j);
                        w1.v = *(const uint4*)((const bf16_t*)src + (size_t)s1 * SW + j);
                        w2.v = *(const uint4*)((const bf16_t*)src + (size_t)s2 * SW + j);
                        w3.v = *(const uint4*)((const bf16_t*)src + (size_t)s3 * SW + j);
                        #pragma unroll
                        for (int k = 0; k < 8; ++k)
                            sum[k] += (us2f(w0.s[k]) + us2f(w1.s[k])) + (us2f(w2.s[k]) + us2f(w3.s[k]));
                    }
                }
                for (; e < c; ++e) {
                    int sn = bp[e];
                    if (SRCF32) {
                        const float* r = (const float*)src + (size_t)sn * SW + j;
                        float4 a = *(const float4*)r;
                        float4 b = *(const float4*)(r + 4);
                        sum[0] += a.x; sum[1] += a.y; sum[2] += a.z; sum[3] += a.w;
                        sum[4] += b.x; sum[5] += b.y; sum[6] += b.z; sum[7] += b.w;
                    } else {
                        U4 w; w.v = *(const uint4*)((const bf16_t*)src + (size_t)sn * SW + j);
                        #pragma unroll
                        for (int k = 0; k < 8; ++k) sum[k] += us2f(w.s[k]);
                    }
                }
            } else {
                if (SRCF32) {
                    const float* r = (const float*)src + (size_t)n * SW + j;
                    float4 a = *(const float4*)r;
                    float4 b = *(const float4*)(r + 4);
                    sum[0] = a.x; sum[1] = a.y; sum[2] = a.z; sum[3] = a.w;
                    sum[4] = b.x; sum[5] = b.y; sum[6] = b.z; sum[7] = b.w;
                } else {
                    U4 w; w.v = *(const uint4*)((const bf16_t*)src + (size_t)n * SW + j);
                    #pragma unroll
                    for (int k = 0; k < 8; ++k) sum[k] = us2f(w.s[k]);
                }
            }
        }
        int cc = (own ? K / 2 : 0) + j;           // column in A's K-space
        int off = (((i >> 5) * KT16 + (cc >> 4)) * 64 + ((cc >> 3) & 1) * 32 + (i & 31)) * 8;
        alignas(16) bf16_t ob[8];
        #pragma unroll
        for (int k = 0; k < 8; ++k) ob[k] = f2b(sum[k]);
        *(uint4*)(&Asl[off]) = *(const uint4*)ob;
    }

    floatx16 acc2[OCT2];
    #pragma unroll
    for (int oo = 0; oo < OCT2; ++oo) acc2[oo] = (floatx16)FZ16;

    __syncthreads();   // Asl + biases ready

    for (int ci = 0; ci < 4; ++ci) {
        // ---- stage 1: wave computes h-tile (ci*8 + wn) x both node-tiles
        floatx16 acc1[2];
        acc1[0] = (floatx16)FZ16;
        acc1[1] = (floatx16)FZ16;

        // rotating 1-ahead prefetch of w1 (global); av (LDS) left to compiler
        const bf16_t* w1p = W1f + (((size_t)(ci * 8 + wn) * KT16) * 64 + lane) * 8;
        short8 w1c = *(const short8*)(w1p);
        #pragma unroll 4
        for (int kk = 0; kk < KT16; ++kk) {
            int kkn = (kk + 1 < KT16) ? kk + 1 : kk;
            short8 w1n = *(const short8*)(w1p + (size_t)kkn * 512);
            short8 av0 = *(const short8*)&Asl[((0 * KT16 + kk) * 64 + lane) * 8];
            acc1[0] = __builtin_amdgcn_mfma_f32_32x32x16_bf16(w1c, av0, acc1[0], 0, 0, 0);
            short8 av1 = *(const short8*)&Asl[((1 * KT16 + kk) * 64 + lane) * 8];
            acc1[1] = __builtin_amdgcn_mfma_f32_32x32x16_bf16(w1c, av1, acc1[1], 0, 0, 0);
            w1c = w1n;
        }

        __syncthreads();   // previous chunk's stage-2 readers done with Hsl

        // bias+relu -> frag-major H; C/D: node=l31, hcol32=(r&3)+8*(r>>2)+4*hi
        #pragma unroll
        for (int nt2 = 0; nt2 < 2; ++nt2) {
            #pragma unroll
            for (int g = 0; g < 4; ++g) {
                float4 bv = *(const float4*)&b1sl[ci * 256 + wn * 32 + 8 * g + 4 * hi];
                const float* bvp = (const float*)&bv;
                alignas(8) bf16_t hb[4];
                #pragma unroll
                for (int e = 0; e < 4; ++e)
                    hb[e] = f2b(fmaxf(acc1[nt2][4 * g + e] + bvp[e], 0.f));
                int off = ((nt2 * 16 + wn * 2 + (g >> 1)) * 64 + (g & 1) * 32 + l31) * 8 + 4 * hi;
                *(uint2*)&Hsl[off] = *(const uint2*)hb;
            }
        }

        __syncthreads();   // H chunk visible

        // ---- stage 2: acc2[oo] += W2(out-tile og*OCT2+oo) x H(node-tile wr)
        // rotating 1-ahead prefetch of the w2 fragment pair
        const bf16_t* w2p = W2f + ((((size_t)(og * OCT2)) * 64 + ci * 16) * 64 + lane) * 8;
        short8 w2c[OCT2];
        #pragma unroll
        for (int oo = 0; oo < OCT2; ++oo)
            w2c[oo] = *(const short8*)(w2p + (size_t)oo * 64 * 512);
        #pragma unroll 4
        for (int ks = 0; ks < 16; ++ks) {
            int ksn = (ks + 1 < 16) ? ks + 1 : ks;
            short8 w2n[OCT2];
            #pragma unroll
            for (int oo = 0; oo < OCT2; ++oo)
                w2n[oo] = *(const short8*)(w2p + ((size_t)oo * 64 + ksn) * 512);
            short8 hf = *(const short8*)&Hsl[((wr * 16 + ks) * 64 + lane) * 8];
            #pragma unroll
            for (int oo = 0; oo < OCT2; ++oo)
                acc2[oo] = __builtin_amdgcn_mfma_f32_32x32x16_bf16(w2c[oo], hf, acc2[oo], 0, 0, 0);
            #pragma unroll
            for (int oo = 0; oo < OCT2; ++oo) w2c[oo] = w2n[oo];
        }
    }

    // ---- epilogue: stage acc2(+bias) into LDS [node][outcol] (padded),
    //      then copy full rows out with coalesced line-aligned stores.
    __syncthreads();   // everyone done reading Hsl/Asl
    {
        const int r = wr * 32 + l31;   // node row within block
        if (F32OUT) {
            float* st = (float*)smem;
            #pragma unroll
            for (int oo = 0; oo < OCT2; ++oo) {
                int o = og * OCT2 + oo;
                #pragma unroll
                for (int g = 0; g < 4; ++g) {
                    int oc = o * 32 + 8 * g + 4 * hi;   // col in NOUT space
                    const bool isInit = (oc >= OH);
                    int col = isInit ? oc - OH : oc;
                    float4 bv = isInit ? *(const float4*)&b2sl[col]
                                       : make_float4(0.f, 0.f, 0.f, 0.f);
                    const float* bvp = (const float*)&bv;
                    float v[4];
                    #pragma unroll
                    for (int e = 0; e < 4; ++e) v[e] = acc2[oo][4 * g + e] + bvp[e];
                    *(float4*)&st[r * STR + oc] = make_float4(v[0], v[1], v[2], v[3]);
                }
            }
        } else {
            bf16_t* st = (bf16_t*)smem;
            #pragma unroll
            for (int oo = 0; oo < OCT2; ++oo) {
                int o = og * OCT2 + oo;
                #pragma unroll
                for (int g = 0; g < 4; ++g) {
                    int oc = o * 32 + 8 * g + 4 * hi;
                    const bool isInit = (oc >= OH);
                    int col = isInit ? oc - OH : oc;
                    float4 bv = isInit ? *(const float4*)&b2sl[col]
                                       : make_float4(0.f, 0.f, 0.f, 0.f);
                    const float* bvp = (const float*)&bv;
                    alignas(8) bf16_t ob[4];
                    #pragma unroll
                    for (int e = 0; e < 4; ++e) ob[e] = f2b(acc2[oo][4 * g + e] + bvp[e]);
                    *(uint2*)&st[r * STR + oc] = *(const uint2*)ob;
                }
            }
        }
    }
    __syncthreads();
    {
        // 16B chunks per node: f32 NOUT*4/16, bf16 NOUT*2/16 -> both 32.
        constexpr int CH = F32OUT ? (NOUT / 4) : (NOUT / 8);
        constexpr int CHH = CH / 2;    // chunks per half-row
        for (int t = tid; t < 64 * CH; t += 512) {
            int nd = t / CH, c = t - (t / CH) * CH;
            int node = bm0 + nd;
            if (node >= NN) continue;
            const bool isInit = (c >= CHH);
            int ch = isInit ? c - CHH : c;
            if (F32OUT) {
                const float* st = (const float*)smem;
                float4 v = *(const float4*)&st[nd * STR + c * 4];
                float* dst = isInit ? (float*)initout : (float*)yout;
                *(float4*)(dst + (size_t)node * OH + ch * 4) = v;
            } else {
                const bf16_t* st = (const bf16_t*)smem;
                uint4 v = *(const uint4*)&st[nd * STR + c * 8];
                bf16_t* dst = isInit ? (bf16_t*)initout : (bf16_t*)yout;
                *(uint4*)(dst + (size_t)node * OH + ch * 8) = v;
            }
        }
    }
}

// ---------------------------------------------------------------------------
// Mean-pool per graph (batch sorted; binary search), h2 bf16.
// 256 threads: 2 node-parallel waves halve the serial node chain.
// ---------------------------------------------------------------------------
__global__ void pool_kernel(const bf16_t* __restrict__ h2,
                            const int* __restrict__ batch,
                            float* __restrict__ enc, int Nn) {
    int g = blockIdx.x;
    __shared__ int s_lo, s_hi;
    __shared__ float part[128];
    if (threadIdx.x == 0) {
        int lo = 0, hi = Nn;
        while (lo < hi) { int mid = (lo + hi) >> 1; if (batch[mid] < g) lo = mid + 1; else hi = mid; }
        s_lo = lo;
        hi = Nn;
        while (lo < hi) { int mid = (lo + hi) >> 1; if (batch[mid] < g + 1) lo = mid + 1; else hi = mid; }
        s_hi = lo;
    }
    __syncthreads();
    int f = threadIdx.x & 127;
    int ty = threadIdx.x >> 7;   // 0..1
    float sum = 0.f;
    for (int n = s_lo + ty; n < s_hi; n += 2) sum += b2f(h2[n * 128 + f]);
    if (ty == 1) part[f] = sum;
    __syncthreads();
    if (ty == 0) {
        float tot = sum + part[f];
        float cnt = (float)((s_hi - s_lo) > 0 ? (s_hi - s_lo) : 1);
        enc[g * 128 + f] = tot / cnt;
    }
}

// ---------------------------------------------------------------------------
// Launch
// ---------------------------------------------------------------------------
extern "C" void kernel_launch(void* const* d_in, const int* in_sizes, int n_in,
                              void* d_out, int out_size, void* d_ws, size_t ws_size,
                              hipStream_t stream) {
    const float* x       = (const float*)d_in[0];
    const int*   ei      = (const int*)d_in[1];
    const int*   batch   = (const int*)d_in[2];
    const float* W1_rel  = (const float*)d_in[3];
    const float* b1      = (const float*)d_in[4];
    const float* W1_root = (const float*)d_in[5];
    const float* W2_rel  = (const float*)d_in[6];
    const float* b2      = (const float*)d_in[7];
    const float* W2_root = (const float*)d_in[8];
    const float* W3_rel  = (const float*)d_in[9];
    const float* b3      = (const float*)d_in[10];
    const float* W3_root = (const float*)d_in[11];
    const float* W4_rel  = (const float*)d_in[12];
    const float* b4      = (const float*)d_in[13];
    const float* W4_root = (const float*)d_in[14];

    float* outF = (float*)d_out;            // [N,64] then [G,128]
    float* enc  = outF + NN * 64;

    char* ws = (char*)d_ws;                         // ~66 MB
    bf16_t* y2buf  = (bf16_t*)(ws + 0);             // [N,128] bf16
    bf16_t* h2init = (bf16_t*)(ws + 12800000ULL);   // [N,128] bf16
    bf16_t* h2buf  = (bf16_t*)(ws + 25600000ULL);   // [N,128] bf16
    float*  y4buf  = (float*)(ws + 38400000ULL);    // [N,64] f32
    int*    cnt    = (int*)(ws + 51200000ULL);      // [N]
    int*    bkt    = (int*)(ws + 51400064ULL);      // [N*64]
    bf16_t* W1f    = (bf16_t*)(ws + 64200064ULL);   // 1024x128 frag-major
    bf16_t* W2f    = (bf16_t*)(ws + 64462208ULL);   // 256x1024 frag-major
    bf16_t* W3f    = (bf16_t*)(ws + 64986496ULL);   // 1024x256 frag-major
    bf16_t* W4f    = (bf16_t*)(ws + 65510784ULL);   // 128x1024 frag-major

    const int RB64 = (NN + 63) / 64;  // 782

    // ---- adjacency + all weight packs in one launch
    hipMemsetAsync(cnt, 0, NN * sizeof(int), stream);
    setup_all<<<NB_BUILD + NB_P1 + NB_P2 + NB_P3 + NB_P4, 256, 0, stream>>>(
        ei, cnt, bkt, W1_rel, W1_root, W2_rel, W2_root,
        W3_rel, W3_root, W4_rel, W4_root, W1f, W2f, W3f, W4f);

    // ---- L1+L2 fused (gather in-prologue): A=[gather(x)|x]; h1 on-chip;
    //      y2 = h1@W2_rel^T (bf16), h2init = h1@W2_root^T + b2 (bf16)
    fused10<128, 256, 0, 1><<<RB64, 512, 0, stream>>>(x, cnt, bkt, W1f, b1, W2f, b2, y2buf, h2init);

    // ---- h2 = relu(h2init + gather(y2));  encoded = mean-pool(h2)
    gather_relu_b16<<<(NN * 16 + 255) / 256, 256, 0, stream>>>(y2buf, h2init, cnt, bkt, h2buf);
    pool_kernel<<<GG, 256, 0, stream>>>(h2buf, batch, enc, NN);

    // ---- L3+L4 fused (gather in-prologue): A=[gather(h2)|h2]; h3 on-chip;
    //      y4 = h3@W4_rel^T (f32), outF = h3@W4_root^T + b4 (f32, direct)
    fused10<256, 128, 1, 0><<<RB64, 512, 0, stream>>>(h2buf, cnt, bkt, W3f, b3, W4f, b4, y4buf, outF);

    // ---- out = outF + gather(y4)
    gather_add_f32_64<<<(NN * 16 + 255) / 256, 256, 0, stream>>>(y4buf, cnt, bkt, outF);
}